// Round 1
// baseline (124.829 us; speedup 1.0000x reference)
//
#include <hip/hip_runtime.h>

// ---------------------------------------------------------------------------
// Tree_42520176230890:
//   feats = x[:, using_idx]            (gather; feature_mask is one-hot.T)
//   d = sigmoid(feats @ W + b)         (16384x1024x1024 GEMM, bf16 MFMA)
//   out[:,0:2]=1 ; mu_L[k] = mu_{L-1}[k>>1] * (k&1 ? 1-d[node] : d[node]),
//     node = 2^L + (k>>1); mu_L written at column offset 2^{L+1}, L=0..9.
//   out: (16384, 2048) f32
// ---------------------------------------------------------------------------

typedef __bf16 bf16x8 __attribute__((ext_vector_type(8)));
typedef float  f32x4  __attribute__((ext_vector_type(4)));

#define BATCH 16384
#define NLEAF 1024
#define FEAT  1024
#define OUTC  2048

__device__ __forceinline__ unsigned short f2bf(float f) {
    union { float f; unsigned int u; } c; c.f = f;
    unsigned int u = c.u;
    u += 0x7FFFu + ((u >> 16) & 1u);   // round-to-nearest-even
    return (unsigned short)(u >> 16);
}

__device__ __forceinline__ void load_lds16(const void* g, void* l) {
    __builtin_amdgcn_global_load_lds(
        (const __attribute__((address_space(1))) unsigned int*)g,
        (__attribute__((address_space(3))) unsigned int*)l, 16, 0, 0);
}

__device__ __forceinline__ float sigmoidf(float z) {
    return 1.0f / (1.0f + __expf(-z));
}

// --- 1. idx[l] = argmax_f feature_mask[f][l] (one-hot -> single writer) ----
__global__ void extract_idx(const float* __restrict__ fm, int* __restrict__ idx) {
    int f = blockIdx.x;          // row of fm (feature)
    int t = threadIdx.x;         // leaf
    if (fm[(size_t)f * NLEAF + t] > 0.5f) idx[t] = f;
}

// --- 2. Wt[n][k] = bf16(W[k][n]) ------------------------------------------
__global__ __launch_bounds__(256) void transpose_w(const float* __restrict__ W,
                                                   short* __restrict__ Wt) {
    __shared__ short tile[64][65];
    int k0 = blockIdx.y * 64, n0 = blockIdx.x * 64;
#pragma unroll
    for (int i = 0; i < 16; ++i) {
        int e = i * 256 + threadIdx.x;
        int kr = e >> 6, nc = e & 63;
        tile[kr][nc] = (short)f2bf(W[(size_t)(k0 + kr) * NLEAF + n0 + nc]);
    }
    __syncthreads();
#pragma unroll
    for (int i = 0; i < 16; ++i) {
        int e = i * 256 + threadIdx.x;
        int nr = e >> 6, kc = e & 63;
        Wt[(size_t)(n0 + nr) * FEAT + k0 + kc] = tile[kc][nr];
    }
}

// --- 3. feats[r][k] = bf16(x[r][idx[k]]) ----------------------------------
__global__ __launch_bounds__(256) void gather_feats(const float* __restrict__ x,
                                                    const int* __restrict__ idx,
                                                    short* __restrict__ feats) {
    int tid = blockIdx.x * 256 + threadIdx.x;   // BATCH*128 threads
    int r  = tid >> 7;
    int kk = (tid & 127) * 8;
    const float* xr = x + (size_t)r * FEAT;
    union { short s[8]; int4 v; } pk;
#pragma unroll
    for (int j = 0; j < 8; ++j) pk.s[j] = (short)f2bf(xr[idx[kk + j]]);
    *(int4*)(feats + (size_t)r * FEAT + kk) = pk.v;
}

// --- 4. GEMM: d = sigmoid(feats @ W + b) -> out[r*2048 + 1024 + c] --------
// 128x128 tile, BK=32, 4 waves (2x2), 16x16x32 bf16 MFMA, global_load_lds,
// LDS layout [row][32] bf16 with 16B-slot XOR swizzle slot^=((row>>1)&3).
__global__ __launch_bounds__(256) void gemm_sigmoid(const short* __restrict__ feats,
                                                    const short* __restrict__ Wt,
                                                    const float* __restrict__ bias,
                                                    float* __restrict__ out) {
    __shared__ __align__(16) short As[128 * 32];
    __shared__ __align__(16) short Bs[128 * 32];

    const int t  = threadIdx.x;
    const int l  = t & 63;
    const int w  = t >> 6;
    const int wr = w >> 1, wc = w & 1;
    const int row0 = (blockIdx.x >> 3) * 128;
    const int n0   = (blockIdx.x & 7) * 128;
    const int lr = l & 15, lk = l >> 4;

    // staging slots (16B units): two per wave per matrix
    const int p0 = (w * 2 + 0) * 64 + l;
    const int p1 = (w * 2 + 1) * 64 + l;
    const int r0 = p0 >> 2, s0 = p0 & 3;
    const int r1 = p1 >> 2, s1 = p1 & 3;
    const int c0 = ((s0 ^ ((r0 >> 1) & 3)) * 8);   // pre-swizzled k offset
    const int c1 = ((s1 ^ ((r1 >> 1) & 3)) * 8);

    // fragment LDS offsets (shorts); swz uniform in m/n since 16|fragment row step
    const int swz = (lr >> 1) & 3;
    int aoff[4], boff[4];
#pragma unroll
    for (int m = 0; m < 4; ++m)
        aoff[m] = (wr * 64 + m * 16 + lr) * 32 + ((lk ^ swz) * 8);
#pragma unroll
    for (int n = 0; n < 4; ++n)
        boff[n] = (wc * 64 + n * 16 + lr) * 32 + ((lk ^ swz) * 8);

    f32x4 acc[4][4];
#pragma unroll
    for (int m = 0; m < 4; ++m)
#pragma unroll
        for (int n = 0; n < 4; ++n)
#pragma unroll
            for (int r = 0; r < 4; ++r) acc[m][n][r] = 0.0f;

    const short* gA0 = feats + (size_t)(row0 + r0) * FEAT + c0;
    const short* gA1 = feats + (size_t)(row0 + r1) * FEAT + c1;
    const short* gB0 = Wt + (size_t)(n0 + r0) * FEAT + c0;
    const short* gB1 = Wt + (size_t)(n0 + r1) * FEAT + c1;

    for (int k0 = 0; k0 < FEAT; k0 += 32) {
        __syncthreads();   // prior compute done before overwrite
        load_lds16(gA0 + k0, As + (w * 2 + 0) * 512);
        load_lds16(gA1 + k0, As + (w * 2 + 1) * 512);
        load_lds16(gB0 + k0, Bs + (w * 2 + 0) * 512);
        load_lds16(gB1 + k0, Bs + (w * 2 + 1) * 512);
        __syncthreads();   // compiler drains vmcnt before barrier

        bf16x8 af[4], bfr[4];
#pragma unroll
        for (int m = 0; m < 4; ++m) af[m]  = *(const bf16x8*)(As + aoff[m]);
#pragma unroll
        for (int n = 0; n < 4; ++n) bfr[n] = *(const bf16x8*)(Bs + boff[n]);
#pragma unroll
        for (int m = 0; m < 4; ++m)
#pragma unroll
            for (int n = 0; n < 4; ++n)
                acc[m][n] = __builtin_amdgcn_mfma_f32_16x16x32_bf16(
                    af[m], bfr[n], acc[m][n], 0, 0, 0);
    }

    // epilogue: +bias, sigmoid, write d into out[row][1024 + col]
#pragma unroll
    for (int m = 0; m < 4; ++m) {
#pragma unroll
        for (int n = 0; n < 4; ++n) {
            int gcol = n0 + wc * 64 + n * 16 + lr;
            float bv = bias[gcol];
#pragma unroll
            for (int r = 0; r < 4; ++r) {
                int grow = row0 + wr * 64 + m * 16 + lk * 4 + r;
                out[(size_t)grow * OUTC + 1024 + gcol] =
                    sigmoidf(acc[m][n][r] + bv);
            }
        }
    }
}

// --- 5. tree expansion: read d from out[r][1024:2048], write full row ------
__global__ __launch_bounds__(256) void expand_tree(float* __restrict__ out) {
    __shared__ float dsm[4][1024];
    __shared__ float tre[4][2048];
    const int t = threadIdx.x;
    const int l = t & 63;
    const int w = t >> 6;
    const int row = blockIdx.x * 4 + w;

    const float* drow = out + (size_t)row * OUTC + 1024;
#pragma unroll
    for (int j = 0; j < 4; ++j)
        ((float4*)&dsm[w][0])[j * 64 + l] = ((const float4*)drow)[j * 64 + l];
    if (l < 2) tre[w][l] = 1.0f;
    __syncthreads();

    for (int L = 0; L < 10; ++L) {
        int n = 2 << L;                       // 2^{L+1}: count and out-offset
        for (int k = l; k < n; k += 64) {
            int node = (1 << L) + (k >> 1);   // parent offset == node
            float dv = dsm[w][node];
            tre[w][n + k] = tre[w][node] * ((k & 1) ? (1.0f - dv) : dv);
        }
        __syncthreads();
    }

    float4* orow = (float4*)(out + (size_t)row * OUTC);
#pragma unroll
    for (int j = 0; j < 8; ++j)
        orow[j * 64 + l] = ((const float4*)&tre[w][0])[j * 64 + l];
}

// --- fallback (tiny workspace): naive fused, one row per block -------------
template <bool HAS_IDX>
__global__ __launch_bounds__(256) void fused_naive(const float* __restrict__ x,
                                                   const float* __restrict__ fm,
                                                   const float* __restrict__ W,
                                                   const float* __restrict__ bias,
                                                   const int* __restrict__ idx,
                                                   float* __restrict__ out) {
    __shared__ float fx[1024];
    __shared__ float dsm[1024];
    __shared__ float tre[2048];
    __shared__ int   idl[1024];
    const int t = threadIdx.x;
    const int row = blockIdx.x;

    if (HAS_IDX) {
        for (int k = t; k < 1024; k += 256) idl[k] = idx[k];
    } else {
        for (int k = t; k < 1024; k += 256) {
            int found = 0;
            for (int f = 0; f < 1024; ++f)
                if (fm[(size_t)f * NLEAF + k] > 0.5f) found = f;
            idl[k] = found;
        }
    }
    __syncthreads();
    const float* xr = x + (size_t)row * FEAT;
    for (int k = t; k < 1024; k += 256) fx[k] = xr[idl[k]];
    __syncthreads();

    float a0 = 0.f, a1 = 0.f, a2 = 0.f, a3 = 0.f;
    for (int k = 0; k < 1024; ++k) {
        float f = fx[k];
        const float* wrp = W + (size_t)k * NLEAF + t;
        a0 = fmaf(f, wrp[0],   a0);
        a1 = fmaf(f, wrp[256], a1);
        a2 = fmaf(f, wrp[512], a2);
        a3 = fmaf(f, wrp[768], a3);
    }
    dsm[t]       = sigmoidf(a0 + bias[t]);
    dsm[t + 256] = sigmoidf(a1 + bias[t + 256]);
    dsm[t + 512] = sigmoidf(a2 + bias[t + 512]);
    dsm[t + 768] = sigmoidf(a3 + bias[t + 768]);
    if (t < 2) tre[t] = 1.0f;
    __syncthreads();

    for (int L = 0; L < 10; ++L) {
        int n = 2 << L;
        for (int k = t; k < n; k += 256) {
            int node = (1 << L) + (k >> 1);
            float dv = dsm[node];
            tre[n + k] = tre[node] * ((k & 1) ? (1.0f - dv) : dv);
        }
        __syncthreads();
    }
    float4* orow = (float4*)(out + (size_t)row * OUTC);
    const float4* ts = (const float4*)tre;
    for (int i = t; i < 512; i += 256) orow[i] = ts[i];
}

extern "C" void kernel_launch(void* const* d_in, const int* in_sizes, int n_in,
                              void* d_out, int out_size, void* d_ws, size_t ws_size,
                              hipStream_t stream) {
    const float* x    = (const float*)d_in[0];
    const float* fm   = (const float*)d_in[1];
    const float* W    = (const float*)d_in[2];
    const float* bias = (const float*)d_in[3];
    float* out = (float*)d_out;

    const size_t IDX_B   = 4096;
    const size_t WT_B    = (size_t)NLEAF * FEAT * 2;        // 2 MiB
    const size_t FEATS_B = (size_t)BATCH * FEAT * 2;        // 32 MiB
    const size_t need = IDX_B + WT_B + FEATS_B;

    if (ws_size >= need) {
        int*   idx   = (int*)d_ws;
        short* Wt    = (short*)((char*)d_ws + IDX_B);
        short* feats = (short*)((char*)d_ws + IDX_B + WT_B);

        extract_idx<<<1024, 1024, 0, stream>>>(fm, idx);
        transpose_w<<<dim3(16, 16), 256, 0, stream>>>(W, Wt);
        gather_feats<<<BATCH * 128 / 256, 256, 0, stream>>>(x, idx, feats);
        gemm_sigmoid<<<(BATCH / 128) * (NLEAF / 128), 256, 0, stream>>>(feats, Wt, bias, out);
        expand_tree<<<BATCH / 4, 256, 0, stream>>>(out);
    } else if (ws_size >= IDX_B) {
        int* idx = (int*)d_ws;
        extract_idx<<<1024, 1024, 0, stream>>>(fm, idx);
        fused_naive<true><<<BATCH, 256, 0, stream>>>(x, fm, W, bias, idx, out);
    } else {
        fused_naive<false><<<BATCH, 256, 0, stream>>>(x, fm, W, bias, nullptr, out);
    }
}